// Round 8
// baseline (13.133 us; speedup 1.0000x reference)
//
#include <hip/hip_runtime.h>

#define BATCH  32
#define S_DIM  16384
#define F_DIM  8
#define K_DIM  9
#define N_DIM  (S_DIM - K_DIM)   // 16375
#define NPB    256               // outputs per block
#define CHUNKS 528               // float4 chunks staged (264 rows x 2 halves)

// Best measured variant (round 2, 12.11 us). Block = 256 threads computes
// 256 consecutive output rows of one batch. Stage rows n0..n0+263 (8448 B)
// into LDS with coalesced float4 loads, XOR-swizzled so wave64 ds_read_b128
// at lane-stride 32B is conflict-free:
//   chunk c = 2*row + half;  byte = (c ^ ((c>>3)&7)) << 4
// (c>>3 == row>>2 always, so read/write swizzles agree.)
//
// Session conclusion: three structurally distinct kernels (global-direct,
// LDS+barrier, barrier-free wave-private) all land at 12.1-12.7 us while
// internal-resource arithmetic bounds kernel-body time at ~5 us. The
// residual is a fixed per-dispatch launch/replay floor — not addressable
// from kernel source at this problem size (32 MB moved).
__global__ __launch_bounds__(256) void peak2peak_kernel(
    const float* __restrict__ x,
    const float* __restrict__ W,
    const float* __restrict__ bias,
    float* __restrict__ out)
{
    __shared__ float4 lds4[CHUNKS];   // 8448 B

    const int t  = threadIdx.x;
    const int b  = blockIdx.y;
    const int n0 = blockIdx.x << 8;

    const float* xbase = x + ((long)b * S_DIM + n0) * F_DIM;
    const int climit = 2 * (S_DIM - n0);   // chunks whose row is in-bounds

#pragma unroll
    for (int i = 0; i < 3; ++i) {
        int c = t + i * 256;
        if (c < CHUNKS && c < climit) {
            float4 v = *reinterpret_cast<const float4*>(xbase + c * 4);
            *reinterpret_cast<float4*>(
                reinterpret_cast<char*>(lds4) + ((c ^ ((c >> 3) & 7)) << 4)) = v;
        }
    }
    __syncthreads();

    const float bb = bias[0];
    float res[F_DIM];

#pragma unroll
    for (int j = 0; j < 2; ++j) {       // feature half: f = 4j .. 4j+3
        float4 rv[8];
#pragma unroll
        for (int k = 0; k < 8; ++k) {
            int row = t + k;
            int byteoff = ((2 * row + j) ^ ((row >> 2) & 7)) << 4;
            rv[k] = *reinterpret_cast<const float4*>(
                reinterpret_cast<const char*>(lds4) + byteoff);
        }
        float rr0[4] = { rv[0].x, rv[0].y, rv[0].z, rv[0].w };
        float basev[4], acc[4];
#pragma unroll
        for (int f = 0; f < 4; ++f) {
            basev[f] = rr0[f] * W[(4 * j + f) * K_DIM];   // W[f,0], scalar loads
            acc[f]   = 0.f;
        }
#pragma unroll
        for (int k = 0; k < 8; ++k) {
            float rr[4] = { rv[k].x, rv[k].y, rv[k].z, rv[k].w };
#pragma unroll
            for (int f = 0; f < 4; ++f) {
                acc[f] += fabsf(basev[f] - rr[f] * W[(4 * j + f) * K_DIM + k + 1]);
            }
        }
#pragma unroll
        for (int f = 0; f < 4; ++f) res[4 * j + f] = acc[f] + bb;
    }

    const int n = n0 + t;
    if (n < N_DIM) {
        float* orow = out + ((long)b * N_DIM + n) * F_DIM;
        float4 o0 = { res[0], res[1], res[2], res[3] };
        float4 o1 = { res[4], res[5], res[6], res[7] };
        *reinterpret_cast<float4*>(orow)     = o0;
        *reinterpret_cast<float4*>(orow + 4) = o1;
    }
}

extern "C" void kernel_launch(void* const* d_in, const int* in_sizes, int n_in,
                              void* d_out, int out_size, void* d_ws, size_t ws_size,
                              hipStream_t stream) {
    const float* x    = (const float*)d_in[0];
    const float* W    = (const float*)d_in[1];
    const float* bias = (const float*)d_in[2];
    float* out        = (float*)d_out;

    dim3 grid(S_DIM / NPB, BATCH);   // 64 x 32 = 2048 blocks
    peak2peak_kernel<<<grid, 256, 0, stream>>>(x, W, bias, out);
}